// Round 3
// baseline (804.391 us; speedup 1.0000x reference)
//
#include <hip/hip_runtime.h>

#define NLVL 16
#define T_MASK ((1u << 19) - 1)
#define NBIN 32768   // 32^3 Morton bins

typedef float v2f __attribute__((ext_vector_type(2)));

__constant__ int c_res[NLVL] = {16, 20, 25, 32, 40, 50, 64, 80,
                                101, 128, 161, 203, 256, 322, 406, 512};
__constant__ int c_off[NLVL] = {0, 4913, 14174, 31750, 67687, 136608, 269259, 543884,
                                1075325, 1599613, 2123901, 2648189, 3172477, 3696765, 4221053, 4745341};
__constant__ float c_grid[NLVL] = {
    (float)(2.0 / 16.0),  (float)(2.0 / 20.0),  (float)(2.0 / 25.0),  (float)(2.0 / 32.0),
    (float)(2.0 / 40.0),  (float)(2.0 / 50.0),  (float)(2.0 / 64.0),  (float)(2.0 / 80.0),
    (float)(2.0 / 101.0), (float)(2.0 / 128.0), (float)(2.0 / 161.0), (float)(2.0 / 203.0),
    (float)(2.0 / 256.0), (float)(2.0 / 322.0), (float)(2.0 / 406.0), (float)(2.0 / 512.0)};

__device__ __forceinline__ void dim_setup(float xv, float grid, int& b, float& w) {
    float xc = fminf(fmaxf(xv, -1.0f), 1.0f);
    float fb = floorf((xc + 1.0f) / grid);
    b = (int)fb;
    float vmin = fb * grid - 1.0f;
    w = (xv - vmin) / grid;   // original xv, exactly as reference
}

__device__ __forceinline__ unsigned part1by2(unsigned v) {
    v &= 0x3ff;
    v = (v | (v << 16)) & 0x030000FFu;
    v = (v | (v << 8))  & 0x0300F00Fu;
    v = (v | (v << 4))  & 0x030C30C3u;
    v = (v | (v << 2))  & 0x09249249u;
    return v;
}

__device__ __forceinline__ unsigned bin3(float a, float b, float c) {
    int ba = (int)floorf((a + 1.0f) * 16.0f); ba = ba < 0 ? 0 : (ba > 31 ? 31 : ba);
    int bb = (int)floorf((b + 1.0f) * 16.0f); bb = bb < 0 ? 0 : (bb > 31 ? 31 : bb);
    int bc = (int)floorf((c + 1.0f) * 16.0f); bc = bc < 0 ? 0 : (bc > 31 ? 31 : bc);
    return part1by2((unsigned)ba) | (part1by2((unsigned)bb) << 1) | (part1by2((unsigned)bc) << 2);
}

// ---- sort pipeline -------------------------------------------------------
__global__ __launch_bounds__(256) void hist_kernel(const float* __restrict__ x,
                                                   unsigned* __restrict__ hist, int n) {
    int p = (int)blockIdx.x * 256 + (int)threadIdx.x;
    if (p >= n) return;
    float a = x[3 * p], b = x[3 * p + 1], c = x[3 * p + 2];
    atomicAdd(&hist[bin3(a, b, c)], 1u);
}

__global__ __launch_bounds__(1024) void scan_kernel(const unsigned* __restrict__ hist,
                                                    unsigned* __restrict__ base) {
    __shared__ unsigned part[1024];
    const int t = (int)threadIdx.x;
    unsigned s = 0;
#pragma unroll
    for (int i = 0; i < NBIN / 1024; ++i) s += hist[t * (NBIN / 1024) + i];
    part[t] = s;
    __syncthreads();
    for (int off = 1; off < 1024; off <<= 1) {
        unsigned v = (t >= off) ? part[t - off] : 0u;
        __syncthreads();
        part[t] += v;
        __syncthreads();
    }
    unsigned run = part[t] - s;   // exclusive base of this thread's bin chunk
    for (int i = 0; i < NBIN / 1024; ++i) {
        unsigned h = hist[t * (NBIN / 1024) + i];
        base[t * (NBIN / 1024) + i] = run;
        run += h;
    }
}

__global__ __launch_bounds__(256) void scatter_kernel(const float* __restrict__ x,
                                                      unsigned* __restrict__ base,
                                                      float* __restrict__ sx, float* __restrict__ sy,
                                                      float* __restrict__ sz, int* __restrict__ org,
                                                      int n) {
    int p = (int)blockIdx.x * 256 + (int)threadIdx.x;
    if (p >= n) return;
    float a = x[3 * p], b = x[3 * p + 1], c = x[3 * p + 2];
    unsigned slot = atomicAdd(&base[bin3(a, b, c)], 1u);
    sx[slot] = a; sy[slot] = b; sz[slot] = c; org[slot] = p;
}

// ---- main gather: one block = one level (of this pass) x 256 sorted points.
// level = blockIdx&7 -> XCD k serves exactly one table (<=4.25 MB, L2-resident).
template <int LV0>
__global__ __launch_bounds__(256) void gather8(const float* __restrict__ sx,
                                               const float* __restrict__ sy,
                                               const float* __restrict__ sz,
                                               const float* __restrict__ tables,
                                               v2f* __restrict__ ws2, int n) {
    const int level = (int)(blockIdx.x & 7) + LV0;
    const int p = (int)(blockIdx.x >> 3) * 256 + (int)threadIdx.x;
    if (p >= n) return;

    const float xx = sx[p], xy = sy[p], xz = sz[p];

    const int res = c_res[level];
    const float grid = c_grid[level];
    const v2f* __restrict__ tab = reinterpret_cast<const v2f*>(tables) + c_off[level];

    int bx, by, bz;
    float wx, wy, wz;
    dim_setup(xx, grid, bx, wx);
    dim_setup(xy, grid, by, wy);
    dim_setup(xz, grid, bz, wz);

    v2f e0, e1, e2, e3, e4, e5, e6, e7;
    if (LV0 == 0) {   // dense: idx = cx*res^2 + cy*res + cz
        const int r2 = res * res;
        const int base = bx * r2 + by * res + bz;
        e0 = tab[base];            e1 = tab[base + 1];
        e2 = tab[base + res];      e3 = tab[base + res + 1];
        e4 = tab[base + r2];       e5 = tab[base + r2 + 1];
        e6 = tab[base + r2 + res]; e7 = tab[base + r2 + res + 1];
    } else {          // hashed
        const unsigned hx0 = (unsigned)bx, hx1 = (unsigned)(bx + 1);
        const unsigned hy0 = (unsigned)by * 2654435761u;
        const unsigned hy1 = (unsigned)(by + 1) * 2654435761u;
        const unsigned hz0 = (unsigned)bz * 805459861u;
        const unsigned hz1 = (unsigned)(bz + 1) * 805459861u;
        e0 = tab[(hx0 ^ hy0 ^ hz0) & T_MASK];
        e1 = tab[(hx0 ^ hy0 ^ hz1) & T_MASK];
        e2 = tab[(hx0 ^ hy1 ^ hz0) & T_MASK];
        e3 = tab[(hx0 ^ hy1 ^ hz1) & T_MASK];
        e4 = tab[(hx1 ^ hy0 ^ hz0) & T_MASK];
        e5 = tab[(hx1 ^ hy0 ^ hz1) & T_MASK];
        e6 = tab[(hx1 ^ hy1 ^ hz0) & T_MASK];
        e7 = tab[(hx1 ^ hy1 ^ hz1) & T_MASK];
    }

    const float ox = 1.0f - wx, oy = 1.0f - wy, oz = 1.0f - wz;
    v2f c00 = e0 * ox + e4 * wx;
    v2f c01 = e1 * ox + e5 * wx;
    v2f c10 = e2 * ox + e6 * wx;
    v2f c11 = e3 * ox + e7 * wx;
    v2f c0 = c00 * oy + c10 * wy;
    v2f c1 = c01 * oy + c11 * wy;
    v2f r = c0 * oz + c1 * wz;

    __builtin_nontemporal_store(r, &ws2[(size_t)(level - LV0) * n + p]);
}

// ---- transpose+scatter: 8 coalesced reads per thread, one 64B row write.
template <int LV0>
__global__ __launch_bounds__(256) void transpose8(const v2f* __restrict__ ws2,
                                                  const int* __restrict__ org,
                                                  float* __restrict__ out, int n) {
    int p = (int)blockIdx.x * 256 + (int)threadIdx.x;
    if (p >= n) return;
    v2f r[8];
#pragma unroll
    for (int l = 0; l < 8; ++l)
        r[l] = __builtin_nontemporal_load(&ws2[(size_t)l * n + p]);
    int o = org[p];
    v2f* dst = reinterpret_cast<v2f*>(out + (size_t)o * 32 + LV0 * 2);
#pragma unroll
    for (int l = 0; l < 8; ++l)
        __builtin_nontemporal_store(r[l], &dst[l]);
}

// ---- safety fallback (ws too small): direct round-0 style kernel ---------
__global__ __launch_bounds__(256) void hashgrid_direct(const float* __restrict__ x,
                                                       const float* __restrict__ tables,
                                                       float* __restrict__ out, int n_points) {
    const int t = (int)blockIdx.x * 256 + (int)threadIdx.x;
    const int p = t >> 4;
    if (p >= n_points) return;
    const int l = t & 15;
    const float xx = x[p * 3 + 0], xy = x[p * 3 + 1], xz = x[p * 3 + 2];
    const int res = c_res[l];
    const float grid = c_grid[l];
    const v2f* __restrict__ tab = reinterpret_cast<const v2f*>(tables) + c_off[l];
    int bx, by, bz; float wx, wy, wz;
    dim_setup(xx, grid, bx, wx);
    dim_setup(xy, grid, by, wy);
    dim_setup(xz, grid, bz, wz);
    v2f e0, e1, e2, e3, e4, e5, e6, e7;
    if (l < 8) {
        const int r2 = res * res;
        const int base = bx * r2 + by * res + bz;
        e0 = tab[base];            e1 = tab[base + 1];
        e2 = tab[base + res];      e3 = tab[base + res + 1];
        e4 = tab[base + r2];       e5 = tab[base + r2 + 1];
        e6 = tab[base + r2 + res]; e7 = tab[base + r2 + res + 1];
    } else {
        const unsigned hx0 = (unsigned)bx, hx1 = (unsigned)(bx + 1);
        const unsigned hy0 = (unsigned)by * 2654435761u, hy1 = (unsigned)(by + 1) * 2654435761u;
        const unsigned hz0 = (unsigned)bz * 805459861u,  hz1 = (unsigned)(bz + 1) * 805459861u;
        e0 = tab[(hx0 ^ hy0 ^ hz0) & T_MASK]; e1 = tab[(hx0 ^ hy0 ^ hz1) & T_MASK];
        e2 = tab[(hx0 ^ hy1 ^ hz0) & T_MASK]; e3 = tab[(hx0 ^ hy1 ^ hz1) & T_MASK];
        e4 = tab[(hx1 ^ hy0 ^ hz0) & T_MASK]; e5 = tab[(hx1 ^ hy0 ^ hz1) & T_MASK];
        e6 = tab[(hx1 ^ hy1 ^ hz0) & T_MASK]; e7 = tab[(hx1 ^ hy1 ^ hz1) & T_MASK];
    }
    const float ox = 1.0f - wx, oy = 1.0f - wy, oz = 1.0f - wz;
    v2f c00 = e0 * ox + e4 * wx, c01 = e1 * ox + e5 * wx;
    v2f c10 = e2 * ox + e6 * wx, c11 = e3 * ox + e7 * wx;
    v2f c0 = c00 * oy + c10 * wy, c1 = c01 * oy + c11 * wy;
    v2f r = c0 * oz + c1 * wz;
    reinterpret_cast<v2f*>(out)[(size_t)p * NLVL + l] = r;
}

extern "C" void kernel_launch(void* const* d_in, const int* in_sizes, int n_in,
                              void* d_out, int out_size, void* d_ws, size_t ws_size,
                              hipStream_t stream) {
    const float* x = (const float*)d_in[0];
    const float* tables = (const float*)d_in[1];
    float* out = (float*)d_out;
    const int n = in_sizes[0] / 3;

    // ws layout: hist(128K) | base(128K) | sx,sy,sz (3*4n) | org (4n) | ws2 (8*n*8)
    const size_t need = 262144 + (size_t)n * 16 + (size_t)n * 64;
    if (ws_size < need) {
        const int blocks = (n * NLVL + 255) / 256;
        hipLaunchKernelGGL(hashgrid_direct, dim3(blocks), dim3(256), 0, stream, x, tables, out, n);
        return;
    }

    char* w = (char*)d_ws;
    unsigned* hist = (unsigned*)w;
    unsigned* base = (unsigned*)(w + 131072);
    float* sx = (float*)(w + 262144);
    float* sy = sx + n;
    float* sz = sy + n;
    int* org = (int*)(sz + n);
    v2f* ws2 = (v2f*)(w + 262144 + (size_t)n * 16);

    const int pb = (n + 255) / 256;   // point-blocks

    hipMemsetAsync(hist, 0, NBIN * sizeof(unsigned), stream);
    hipLaunchKernelGGL(hist_kernel, dim3(pb), dim3(256), 0, stream, x, hist, n);
    hipLaunchKernelGGL(scan_kernel, dim3(1), dim3(1024), 0, stream, hist, base);
    hipLaunchKernelGGL(scatter_kernel, dim3(pb), dim3(256), 0, stream, x, base, sx, sy, sz, org, n);

    hipLaunchKernelGGL(gather8<0>, dim3(pb * 8), dim3(256), 0, stream, sx, sy, sz, tables, ws2, n);
    hipLaunchKernelGGL(transpose8<0>, dim3(pb), dim3(256), 0, stream, ws2, org, out, n);
    hipLaunchKernelGGL(gather8<8>, dim3(pb * 8), dim3(256), 0, stream, sx, sy, sz, tables, ws2, n);
    hipLaunchKernelGGL(transpose8<8>, dim3(pb), dim3(256), 0, stream, ws2, org, out, n);
}

// Round 4
// 724.393 us; speedup vs baseline: 1.1104x; 1.1104x over previous
//
#include <hip/hip_runtime.h>

#define NLVL 16
#define T_MASK ((1u << 19) - 1)
#define NBIN 32768   // 32^3 Morton bins

typedef float v2f __attribute__((ext_vector_type(2)));
typedef float v4f __attribute__((ext_vector_type(4)));

// Runtime-indexed copies (hash kernel, fallback)
__constant__ int c_res[NLVL] = {16, 20, 25, 32, 40, 50, 64, 80,
                                101, 128, 161, 203, 256, 322, 406, 512};
__constant__ int c_off[NLVL] = {0, 4913, 14174, 31750, 67687, 136608, 269259, 543884,
                                1075325, 1599613, 2123901, 2648189, 3172477, 3696765, 4221053, 4745341};
__constant__ float c_grid[NLVL] = {
    (float)(2.0 / 16.0),  (float)(2.0 / 20.0),  (float)(2.0 / 25.0),  (float)(2.0 / 32.0),
    (float)(2.0 / 40.0),  (float)(2.0 / 50.0),  (float)(2.0 / 64.0),  (float)(2.0 / 80.0),
    (float)(2.0 / 101.0), (float)(2.0 / 128.0), (float)(2.0 / 161.0), (float)(2.0 / 203.0),
    (float)(2.0 / 256.0), (float)(2.0 / 322.0), (float)(2.0 / 406.0), (float)(2.0 / 512.0)};

// Compile-time copies (dense epilogue, fully unrolled -> immediates)
constexpr int kRes[8] = {16, 20, 25, 32, 40, 50, 64, 80};
constexpr int kOff[8] = {0, 4913, 14174, 31750, 67687, 136608, 269259, 543884};
constexpr float kGrid[8] = {
    (float)(2.0 / 16.0), (float)(2.0 / 20.0), (float)(2.0 / 25.0), (float)(2.0 / 32.0),
    (float)(2.0 / 40.0), (float)(2.0 / 50.0), (float)(2.0 / 64.0), (float)(2.0 / 80.0)};

__device__ __forceinline__ void dim_setup(float xv, float grid, int& b, float& w) {
    float xc = fminf(fmaxf(xv, -1.0f), 1.0f);
    float fb = floorf((xc + 1.0f) / grid);
    b = (int)fb;
    float vmin = fb * grid - 1.0f;
    w = (xv - vmin) / grid;   // original xv, exactly as reference
}

__device__ __forceinline__ unsigned part1by2(unsigned v) {
    v &= 0x3ff;
    v = (v | (v << 16)) & 0x030000FFu;
    v = (v | (v << 8))  & 0x0300F00Fu;
    v = (v | (v << 4))  & 0x030C30C3u;
    v = (v | (v << 2))  & 0x09249249u;
    return v;
}

__device__ __forceinline__ unsigned bin3(float a, float b, float c) {
    int ba = (int)floorf((a + 1.0f) * 16.0f); ba = ba < 0 ? 0 : (ba > 31 ? 31 : ba);
    int bb = (int)floorf((b + 1.0f) * 16.0f); bb = bb < 0 ? 0 : (bb > 31 ? 31 : bb);
    int bc = (int)floorf((c + 1.0f) * 16.0f); bc = bc < 0 ? 0 : (bc > 31 ? 31 : bc);
    return part1by2((unsigned)ba) | (part1by2((unsigned)bb) << 1) | (part1by2((unsigned)bc) << 2);
}

// ---- sort pipeline -------------------------------------------------------
__global__ __launch_bounds__(256) void hist_kernel(const float* __restrict__ x,
                                                   unsigned* __restrict__ hist, int n) {
    int p = (int)blockIdx.x * 256 + (int)threadIdx.x;
    if (p >= n) return;
    float a = x[3 * p], b = x[3 * p + 1], c = x[3 * p + 2];
    atomicAdd(&hist[bin3(a, b, c)], 1u);
}

__global__ __launch_bounds__(1024) void scan_kernel(const unsigned* __restrict__ hist,
                                                    unsigned* __restrict__ base) {
    __shared__ unsigned part[1024];
    const int t = (int)threadIdx.x;
    unsigned s = 0;
#pragma unroll
    for (int i = 0; i < NBIN / 1024; ++i) s += hist[t * (NBIN / 1024) + i];
    part[t] = s;
    __syncthreads();
    for (int off = 1; off < 1024; off <<= 1) {
        unsigned v = (t >= off) ? part[t - off] : 0u;
        __syncthreads();
        part[t] += v;
        __syncthreads();
    }
    unsigned run = part[t] - s;
    for (int i = 0; i < NBIN / 1024; ++i) {
        unsigned h = hist[t * (NBIN / 1024) + i];
        base[t * (NBIN / 1024) + i] = run;
        run += h;
    }
}

__global__ __launch_bounds__(256) void scatter_kernel(const float* __restrict__ x,
                                                      unsigned* __restrict__ base,
                                                      v4f* __restrict__ pts, int n) {
    int p = (int)blockIdx.x * 256 + (int)threadIdx.x;
    if (p >= n) return;
    float a = x[3 * p], b = x[3 * p + 1], c = x[3 * p + 2];
    unsigned slot = atomicAdd(&base[bin3(a, b, c)], 1u);
    v4f v; v.x = a; v.y = b; v.z = c; v.w = __int_as_float(p);
    pts[slot] = v;
}

// ---- hashed levels: one block = one level x 256 sorted points.
// level = (blockIdx&7)+8 -> XCD k serves exactly one 4 MB table (L2-resident).
__global__ __launch_bounds__(256) void gather_hash(const v4f* __restrict__ pts,
                                                   const float* __restrict__ tables,
                                                   v2f* __restrict__ ws2, int n) {
    const int level = (int)(blockIdx.x & 7) + 8;
    const int p = (int)(blockIdx.x >> 3) * 256 + (int)threadIdx.x;
    if (p >= n) return;

    const v4f pt = pts[p];
    const float grid = c_grid[level];
    const v2f* __restrict__ tab = reinterpret_cast<const v2f*>(tables) + c_off[level];

    int bx, by, bz;
    float wx, wy, wz;
    dim_setup(pt.x, grid, bx, wx);
    dim_setup(pt.y, grid, by, wy);
    dim_setup(pt.z, grid, bz, wz);

    const unsigned hx0 = (unsigned)bx, hx1 = (unsigned)(bx + 1);
    const unsigned hy0 = (unsigned)by * 2654435761u;
    const unsigned hy1 = (unsigned)(by + 1) * 2654435761u;
    const unsigned hz0 = (unsigned)bz * 805459861u;
    const unsigned hz1 = (unsigned)(bz + 1) * 805459861u;
    v2f e0 = tab[(hx0 ^ hy0 ^ hz0) & T_MASK];
    v2f e1 = tab[(hx0 ^ hy0 ^ hz1) & T_MASK];
    v2f e2 = tab[(hx0 ^ hy1 ^ hz0) & T_MASK];
    v2f e3 = tab[(hx0 ^ hy1 ^ hz1) & T_MASK];
    v2f e4 = tab[(hx1 ^ hy0 ^ hz0) & T_MASK];
    v2f e5 = tab[(hx1 ^ hy0 ^ hz1) & T_MASK];
    v2f e6 = tab[(hx1 ^ hy1 ^ hz0) & T_MASK];
    v2f e7 = tab[(hx1 ^ hy1 ^ hz1) & T_MASK];

    const float ox = 1.0f - wx, oy = 1.0f - wy, oz = 1.0f - wz;
    v2f c00 = e0 * ox + e4 * wx;
    v2f c01 = e1 * ox + e5 * wx;
    v2f c10 = e2 * ox + e6 * wx;
    v2f c11 = e3 * ox + e7 * wx;
    v2f c0 = c00 * oy + c10 * wy;
    v2f c1 = c01 * oy + c11 * wy;
    v2f r = c0 * oz + c1 * wz;

    __builtin_nontemporal_store(r, &ws2[(size_t)(level - 8) * n + p]);
}

// ---- dense levels + final row assembly: one thread = one sorted point.
// Computes levels 0-7 inline (constexpr-unrolled), reads hashed results from
// ws2 (coalesced), writes the full 128 B row to out[org]. Bijective XCD-chunk
// swizzle gives each XCD a contiguous Morton range -> dense tables L2-local.
__global__ __launch_bounds__(256) void dense_finish(const v4f* __restrict__ pts,
                                                    const float* __restrict__ tables,
                                                    const v2f* __restrict__ ws2,
                                                    float* __restrict__ out, int n) {
    const int nb = (int)gridDim.x;
    const int bid = (int)blockIdx.x;
    const int q = nb >> 3, r = nb & 7;
    const int xcd = bid & 7, j = bid >> 3;
    const int nbid = (xcd < r) ? xcd * (q + 1) + j : r * (q + 1) + (xcd - r) * q + j;
    const int p = nbid * 256 + (int)threadIdx.x;
    if (p >= n) return;

    const v4f pt = pts[p];
    const int org = __float_as_int(pt.w);

    v2f d[8];
#pragma unroll
    for (int l = 0; l < 8; ++l) {
        const int res = kRes[l];
        const float grid = kGrid[l];
        const v2f* __restrict__ tab = reinterpret_cast<const v2f*>(tables) + kOff[l];
        int bx, by, bz;
        float wx, wy, wz;
        dim_setup(pt.x, grid, bx, wx);
        dim_setup(pt.y, grid, by, wy);
        dim_setup(pt.z, grid, bz, wz);
        const int r2 = res * res;
        const int base = bx * r2 + by * res + bz;
        v2f e0 = tab[base];            v2f e1 = tab[base + 1];
        v2f e2 = tab[base + res];      v2f e3 = tab[base + res + 1];
        v2f e4 = tab[base + r2];       v2f e5 = tab[base + r2 + 1];
        v2f e6 = tab[base + r2 + res]; v2f e7 = tab[base + r2 + res + 1];
        const float ox = 1.0f - wx, oy = 1.0f - wy, oz = 1.0f - wz;
        v2f c00 = e0 * ox + e4 * wx;
        v2f c01 = e1 * ox + e5 * wx;
        v2f c10 = e2 * ox + e6 * wx;
        v2f c11 = e3 * ox + e7 * wx;
        v2f c0 = c00 * oy + c10 * wy;
        v2f c1 = c01 * oy + c11 * wy;
        d[l] = c0 * oz + c1 * wz;
    }

    v2f h[8];
#pragma unroll
    for (int l = 0; l < 8; ++l)
        h[l] = __builtin_nontemporal_load(&ws2[(size_t)l * n + p]);

    v4f* dst = reinterpret_cast<v4f*>(out + (size_t)org * 32);
#pragma unroll
    for (int k = 0; k < 4; ++k) {
        v4f v; v.x = d[2 * k].x; v.y = d[2 * k].y; v.z = d[2 * k + 1].x; v.w = d[2 * k + 1].y;
        __builtin_nontemporal_store(v, &dst[k]);
    }
#pragma unroll
    for (int k = 0; k < 4; ++k) {
        v4f v; v.x = h[2 * k].x; v.y = h[2 * k].y; v.z = h[2 * k + 1].x; v.w = h[2 * k + 1].y;
        __builtin_nontemporal_store(v, &dst[4 + k]);
    }
}

// ---- safety fallback (ws too small) --------------------------------------
__global__ __launch_bounds__(256) void hashgrid_direct(const float* __restrict__ x,
                                                       const float* __restrict__ tables,
                                                       float* __restrict__ out, int n_points) {
    const int t = (int)blockIdx.x * 256 + (int)threadIdx.x;
    const int p = t >> 4;
    if (p >= n_points) return;
    const int l = t & 15;
    const float xx = x[p * 3 + 0], xy = x[p * 3 + 1], xz = x[p * 3 + 2];
    const int res = c_res[l];
    const float grid = c_grid[l];
    const v2f* __restrict__ tab = reinterpret_cast<const v2f*>(tables) + c_off[l];
    int bx, by, bz; float wx, wy, wz;
    dim_setup(xx, grid, bx, wx);
    dim_setup(xy, grid, by, wy);
    dim_setup(xz, grid, bz, wz);
    v2f e0, e1, e2, e3, e4, e5, e6, e7;
    if (l < 8) {
        const int r2 = res * res;
        const int base = bx * r2 + by * res + bz;
        e0 = tab[base];            e1 = tab[base + 1];
        e2 = tab[base + res];      e3 = tab[base + res + 1];
        e4 = tab[base + r2];       e5 = tab[base + r2 + 1];
        e6 = tab[base + r2 + res]; e7 = tab[base + r2 + res + 1];
    } else {
        const unsigned hx0 = (unsigned)bx, hx1 = (unsigned)(bx + 1);
        const unsigned hy0 = (unsigned)by * 2654435761u, hy1 = (unsigned)(by + 1) * 2654435761u;
        const unsigned hz0 = (unsigned)bz * 805459861u,  hz1 = (unsigned)(bz + 1) * 805459861u;
        e0 = tab[(hx0 ^ hy0 ^ hz0) & T_MASK]; e1 = tab[(hx0 ^ hy0 ^ hz1) & T_MASK];
        e2 = tab[(hx0 ^ hy1 ^ hz0) & T_MASK]; e3 = tab[(hx0 ^ hy1 ^ hz1) & T_MASK];
        e4 = tab[(hx1 ^ hy0 ^ hz0) & T_MASK]; e5 = tab[(hx1 ^ hy0 ^ hz1) & T_MASK];
        e6 = tab[(hx1 ^ hy1 ^ hz0) & T_MASK]; e7 = tab[(hx1 ^ hy1 ^ hz1) & T_MASK];
    }
    const float ox = 1.0f - wx, oy = 1.0f - wy, oz = 1.0f - wz;
    v2f c00 = e0 * ox + e4 * wx, c01 = e1 * ox + e5 * wx;
    v2f c10 = e2 * ox + e6 * wx, c11 = e3 * ox + e7 * wx;
    v2f c0 = c00 * oy + c10 * wy, c1 = c01 * oy + c11 * wy;
    v2f r = c0 * oz + c1 * wz;
    reinterpret_cast<v2f*>(out)[(size_t)p * NLVL + l] = r;
}

extern "C" void kernel_launch(void* const* d_in, const int* in_sizes, int n_in,
                              void* d_out, int out_size, void* d_ws, size_t ws_size,
                              hipStream_t stream) {
    const float* x = (const float*)d_in[0];
    const float* tables = (const float*)d_in[1];
    float* out = (float*)d_out;
    const int n = in_sizes[0] / 3;

    // ws layout: hist(128K) | base(128K) | pts float4 (16n) | ws2 (8 levels * 8B * n)
    const size_t need = 262144 + (size_t)n * 16 + (size_t)n * 64;
    if (ws_size < need) {
        const int blocks = (n * NLVL + 255) / 256;
        hipLaunchKernelGGL(hashgrid_direct, dim3(blocks), dim3(256), 0, stream, x, tables, out, n);
        return;
    }

    char* w = (char*)d_ws;
    unsigned* hist = (unsigned*)w;
    unsigned* base = (unsigned*)(w + 131072);
    v4f* pts = (v4f*)(w + 262144);
    v2f* ws2 = (v2f*)(w + 262144 + (size_t)n * 16);

    const int pb = (n + 255) / 256;

    hipMemsetAsync(hist, 0, NBIN * sizeof(unsigned), stream);
    hipLaunchKernelGGL(hist_kernel, dim3(pb), dim3(256), 0, stream, x, hist, n);
    hipLaunchKernelGGL(scan_kernel, dim3(1), dim3(1024), 0, stream, hist, base);
    hipLaunchKernelGGL(scatter_kernel, dim3(pb), dim3(256), 0, stream, x, base, pts, n);

    hipLaunchKernelGGL(gather_hash, dim3(pb * 8), dim3(256), 0, stream, pts, tables, ws2, n);
    hipLaunchKernelGGL(dense_finish, dim3(pb), dim3(256), 0, stream, pts, tables, ws2, out, n);
}

// Round 5
// 467.273 us; speedup vs baseline: 1.7215x; 1.5503x over previous
//
#include <hip/hip_runtime.h>

#define NLVL 16
#define T_MASK ((1u << 19) - 1)
#define NBIN 32768   // 32^3 Morton bins

typedef float v2f __attribute__((ext_vector_type(2)));
typedef float v4f __attribute__((ext_vector_type(4)));

// Runtime-indexed copies (hash kernel, fallback)
__constant__ int c_res[NLVL] = {16, 20, 25, 32, 40, 50, 64, 80,
                                101, 128, 161, 203, 256, 322, 406, 512};
__constant__ int c_off[NLVL] = {0, 4913, 14174, 31750, 67687, 136608, 269259, 543884,
                                1075325, 1599613, 2123901, 2648189, 3172477, 3696765, 4221053, 4745341};
__constant__ float c_grid[NLVL] = {
    (float)(2.0 / 16.0),  (float)(2.0 / 20.0),  (float)(2.0 / 25.0),  (float)(2.0 / 32.0),
    (float)(2.0 / 40.0),  (float)(2.0 / 50.0),  (float)(2.0 / 64.0),  (float)(2.0 / 80.0),
    (float)(2.0 / 101.0), (float)(2.0 / 128.0), (float)(2.0 / 161.0), (float)(2.0 / 203.0),
    (float)(2.0 / 256.0), (float)(2.0 / 322.0), (float)(2.0 / 406.0), (float)(2.0 / 512.0)};

// Compile-time copies (dense epilogue, fully unrolled -> immediates)
constexpr int kRes[8] = {16, 20, 25, 32, 40, 50, 64, 80};
constexpr int kOff[8] = {0, 4913, 14174, 31750, 67687, 136608, 269259, 543884};
constexpr float kGrid[8] = {
    (float)(2.0 / 16.0), (float)(2.0 / 20.0), (float)(2.0 / 25.0), (float)(2.0 / 32.0),
    (float)(2.0 / 40.0), (float)(2.0 / 50.0), (float)(2.0 / 64.0), (float)(2.0 / 80.0)};

__device__ __forceinline__ void dim_setup(float xv, float grid, int& b, float& w) {
    float xc = fminf(fmaxf(xv, -1.0f), 1.0f);
    float fb = floorf((xc + 1.0f) / grid);
    b = (int)fb;
    float vmin = fb * grid - 1.0f;
    w = (xv - vmin) / grid;   // original xv, exactly as reference
}

__device__ __forceinline__ unsigned part1by2(unsigned v) {
    v &= 0x3ff;
    v = (v | (v << 16)) & 0x030000FFu;
    v = (v | (v << 8))  & 0x0300F00Fu;
    v = (v | (v << 4))  & 0x030C30C3u;
    v = (v | (v << 2))  & 0x09249249u;
    return v;
}

__device__ __forceinline__ unsigned bin3(float a, float b, float c) {
    int ba = (int)floorf((a + 1.0f) * 16.0f); ba = ba < 0 ? 0 : (ba > 31 ? 31 : ba);
    int bb = (int)floorf((b + 1.0f) * 16.0f); bb = bb < 0 ? 0 : (bb > 31 ? 31 : bb);
    int bc = (int)floorf((c + 1.0f) * 16.0f); bc = bc < 0 ? 0 : (bc > 31 ? 31 : bc);
    return part1by2((unsigned)ba) | (part1by2((unsigned)bb) << 1) | (part1by2((unsigned)bc) << 2);
}

// ---- sort pipeline -------------------------------------------------------
__global__ __launch_bounds__(256) void hist_kernel(const float* __restrict__ x,
                                                   unsigned* __restrict__ hist, int n) {
    int p = (int)blockIdx.x * 256 + (int)threadIdx.x;
    if (p >= n) return;
    float a = x[3 * p], b = x[3 * p + 1], c = x[3 * p + 2];
    atomicAdd(&hist[bin3(a, b, c)], 1u);
}

__global__ __launch_bounds__(1024) void scan_kernel(const unsigned* __restrict__ hist,
                                                    unsigned* __restrict__ base) {
    __shared__ unsigned part[1024];
    const int t = (int)threadIdx.x;
    unsigned s = 0;
#pragma unroll
    for (int i = 0; i < NBIN / 1024; ++i) s += hist[t * (NBIN / 1024) + i];
    part[t] = s;
    __syncthreads();
    for (int off = 1; off < 1024; off <<= 1) {
        unsigned v = (t >= off) ? part[t - off] : 0u;
        __syncthreads();
        part[t] += v;
        __syncthreads();
    }
    unsigned run = part[t] - s;
    for (int i = 0; i < NBIN / 1024; ++i) {
        unsigned h = hist[t * (NBIN / 1024) + i];
        base[t * (NBIN / 1024) + i] = run;
        run += h;
    }
}

__global__ __launch_bounds__(256) void scatter_kernel(const float* __restrict__ x,
                                                      unsigned* __restrict__ base,
                                                      v4f* __restrict__ pts, int n) {
    int p = (int)blockIdx.x * 256 + (int)threadIdx.x;
    if (p >= n) return;
    float a = x[3 * p], b = x[3 * p + 1], c = x[3 * p + 2];
    unsigned slot = atomicAdd(&base[bin3(a, b, c)], 1u);
    v4f v; v.x = a; v.y = b; v.z = c; v.w = __int_as_float(p);
    pts[slot] = v;
}

// ---- hashed levels: one block = one level x 256 sorted points.
// level = (blockIdx&7)+8 -> XCD k serves exactly one 4 MB table (L2-resident).
__global__ __launch_bounds__(256) void gather_hash(const v4f* __restrict__ pts,
                                                   const float* __restrict__ tables,
                                                   v2f* __restrict__ ws2, int n) {
    const int level = (int)(blockIdx.x & 7) + 8;
    const int p = (int)(blockIdx.x >> 3) * 256 + (int)threadIdx.x;
    if (p >= n) return;

    const v4f pt = __builtin_nontemporal_load(&pts[p]);   // single-use stream
    const float grid = c_grid[level];
    const v2f* __restrict__ tab = reinterpret_cast<const v2f*>(tables) + c_off[level];

    int bx, by, bz;
    float wx, wy, wz;
    dim_setup(pt.x, grid, bx, wx);
    dim_setup(pt.y, grid, by, wy);
    dim_setup(pt.z, grid, bz, wz);

    const unsigned hx0 = (unsigned)bx, hx1 = (unsigned)(bx + 1);
    const unsigned hy0 = (unsigned)by * 2654435761u;
    const unsigned hy1 = (unsigned)(by + 1) * 2654435761u;
    const unsigned hz0 = (unsigned)bz * 805459861u;
    const unsigned hz1 = (unsigned)(bz + 1) * 805459861u;
    v2f e0 = tab[(hx0 ^ hy0 ^ hz0) & T_MASK];
    v2f e1 = tab[(hx0 ^ hy0 ^ hz1) & T_MASK];
    v2f e2 = tab[(hx0 ^ hy1 ^ hz0) & T_MASK];
    v2f e3 = tab[(hx0 ^ hy1 ^ hz1) & T_MASK];
    v2f e4 = tab[(hx1 ^ hy0 ^ hz0) & T_MASK];
    v2f e5 = tab[(hx1 ^ hy0 ^ hz1) & T_MASK];
    v2f e6 = tab[(hx1 ^ hy1 ^ hz0) & T_MASK];
    v2f e7 = tab[(hx1 ^ hy1 ^ hz1) & T_MASK];

    const float ox = 1.0f - wx, oy = 1.0f - wy, oz = 1.0f - wz;
    v2f c00 = e0 * ox + e4 * wx;
    v2f c01 = e1 * ox + e5 * wx;
    v2f c10 = e2 * ox + e6 * wx;
    v2f c11 = e3 * ox + e7 * wx;
    v2f c0 = c00 * oy + c10 * wy;
    v2f c1 = c01 * oy + c11 * wy;
    v2f r = c0 * oz + c1 * wz;

    // lane-contiguous -> wave-coalesced full lines; NT keeps tables resident
    __builtin_nontemporal_store(r, &ws2[(size_t)(level - 8) * n + p]);
}

// ---- dense levels + final row assembly: one thread = one sorted point.
// Regular (cached) stores for the scattered 128 B rows: L2 merges the 8x16 B
// into 2 fully-dirty lines -> compulsory 128 MB write-back (NT stores gave
// 3.9x write amplification in round 4).
__global__ __launch_bounds__(256) void dense_finish(const v4f* __restrict__ pts,
                                                    const float* __restrict__ tables,
                                                    const v2f* __restrict__ ws2,
                                                    float* __restrict__ out, int n) {
    const int nb = (int)gridDim.x;
    const int bid = (int)blockIdx.x;
    const int q = nb >> 3, r = nb & 7;
    const int xcd = bid & 7, j = bid >> 3;
    const int nbid = (xcd < r) ? xcd * (q + 1) + j : r * (q + 1) + (xcd - r) * q + j;
    const int p = nbid * 256 + (int)threadIdx.x;
    if (p >= n) return;

    const v4f pt = __builtin_nontemporal_load(&pts[p]);
    const int org = __float_as_int(pt.w);

    v2f d[8];
#pragma unroll
    for (int l = 0; l < 8; ++l) {
        const int res = kRes[l];
        const float grid = kGrid[l];
        const v2f* __restrict__ tab = reinterpret_cast<const v2f*>(tables) + kOff[l];
        int bx, by, bz;
        float wx, wy, wz;
        dim_setup(pt.x, grid, bx, wx);
        dim_setup(pt.y, grid, by, wy);
        dim_setup(pt.z, grid, bz, wz);
        const int r2 = res * res;
        const int base = bx * r2 + by * res + bz;
        v2f e0 = tab[base];            v2f e1 = tab[base + 1];
        v2f e2 = tab[base + res];      v2f e3 = tab[base + res + 1];
        v2f e4 = tab[base + r2];       v2f e5 = tab[base + r2 + 1];
        v2f e6 = tab[base + r2 + res]; v2f e7 = tab[base + r2 + res + 1];
        const float ox = 1.0f - wx, oy = 1.0f - wy, oz = 1.0f - wz;
        v2f c00 = e0 * ox + e4 * wx;
        v2f c01 = e1 * ox + e5 * wx;
        v2f c10 = e2 * ox + e6 * wx;
        v2f c11 = e3 * ox + e7 * wx;
        v2f c0 = c00 * oy + c10 * wy;
        v2f c1 = c01 * oy + c11 * wy;
        d[l] = c0 * oz + c1 * wz;
    }

    v2f h[8];
#pragma unroll
    for (int l = 0; l < 8; ++l)
        h[l] = __builtin_nontemporal_load(&ws2[(size_t)l * n + p]);

    v4f* dst = reinterpret_cast<v4f*>(out + (size_t)org * 32);
#pragma unroll
    for (int k = 0; k < 4; ++k) {
        v4f v; v.x = d[2 * k].x; v.y = d[2 * k].y; v.z = d[2 * k + 1].x; v.w = d[2 * k + 1].y;
        dst[k] = v;                       // cached store -> L2 write-combining
    }
#pragma unroll
    for (int k = 0; k < 4; ++k) {
        v4f v; v.x = h[2 * k].x; v.y = h[2 * k].y; v.z = h[2 * k + 1].x; v.w = h[2 * k + 1].y;
        dst[4 + k] = v;
    }
}

// ---- safety fallback (ws too small) --------------------------------------
__global__ __launch_bounds__(256) void hashgrid_direct(const float* __restrict__ x,
                                                       const float* __restrict__ tables,
                                                       float* __restrict__ out, int n_points) {
    const int t = (int)blockIdx.x * 256 + (int)threadIdx.x;
    const int p = t >> 4;
    if (p >= n_points) return;
    const int l = t & 15;
    const float xx = x[p * 3 + 0], xy = x[p * 3 + 1], xz = x[p * 3 + 2];
    const int res = c_res[l];
    const float grid = c_grid[l];
    const v2f* __restrict__ tab = reinterpret_cast<const v2f*>(tables) + c_off[l];
    int bx, by, bz; float wx, wy, wz;
    dim_setup(xx, grid, bx, wx);
    dim_setup(xy, grid, by, wy);
    dim_setup(xz, grid, bz, wz);
    v2f e0, e1, e2, e3, e4, e5, e6, e7;
    if (l < 8) {
        const int r2 = res * res;
        const int base = bx * r2 + by * res + bz;
        e0 = tab[base];            e1 = tab[base + 1];
        e2 = tab[base + res];      e3 = tab[base + res + 1];
        e4 = tab[base + r2];       e5 = tab[base + r2 + 1];
        e6 = tab[base + r2 + res]; e7 = tab[base + r2 + res + 1];
    } else {
        const unsigned hx0 = (unsigned)bx, hx1 = (unsigned)(bx + 1);
        const unsigned hy0 = (unsigned)by * 2654435761u, hy1 = (unsigned)(by + 1) * 2654435761u;
        const unsigned hz0 = (unsigned)bz * 805459861u,  hz1 = (unsigned)(bz + 1) * 805459861u;
        e0 = tab[(hx0 ^ hy0 ^ hz0) & T_MASK]; e1 = tab[(hx0 ^ hy0 ^ hz1) & T_MASK];
        e2 = tab[(hx0 ^ hy1 ^ hz0) & T_MASK]; e3 = tab[(hx0 ^ hy1 ^ hz1) & T_MASK];
        e4 = tab[(hx1 ^ hy0 ^ hz0) & T_MASK]; e5 = tab[(hx1 ^ hy0 ^ hz1) & T_MASK];
        e6 = tab[(hx1 ^ hy1 ^ hz0) & T_MASK]; e7 = tab[(hx1 ^ hy1 ^ hz1) & T_MASK];
    }
    const float ox = 1.0f - wx, oy = 1.0f - wy, oz = 1.0f - wz;
    v2f c00 = e0 * ox + e4 * wx, c01 = e1 * ox + e5 * wx;
    v2f c10 = e2 * ox + e6 * wx, c11 = e3 * ox + e7 * wx;
    v2f c0 = c00 * oy + c10 * wy, c1 = c01 * oy + c11 * wy;
    v2f r = c0 * oz + c1 * wz;
    reinterpret_cast<v2f*>(out)[(size_t)p * NLVL + l] = r;
}

extern "C" void kernel_launch(void* const* d_in, const int* in_sizes, int n_in,
                              void* d_out, int out_size, void* d_ws, size_t ws_size,
                              hipStream_t stream) {
    const float* x = (const float*)d_in[0];
    const float* tables = (const float*)d_in[1];
    float* out = (float*)d_out;
    const int n = in_sizes[0] / 3;

    // ws layout: hist(128K) | base(128K) | pts float4 (16n) | ws2 (8 levels * 8B * n)
    const size_t need = 262144 + (size_t)n * 16 + (size_t)n * 64;
    if (ws_size < need) {
        const int blocks = (n * NLVL + 255) / 256;
        hipLaunchKernelGGL(hashgrid_direct, dim3(blocks), dim3(256), 0, stream, x, tables, out, n);
        return;
    }

    char* w = (char*)d_ws;
    unsigned* hist = (unsigned*)w;
    unsigned* base = (unsigned*)(w + 131072);
    v4f* pts = (v4f*)(w + 262144);
    v2f* ws2 = (v2f*)(w + 262144 + (size_t)n * 16);

    const int pb = (n + 255) / 256;

    hipMemsetAsync(hist, 0, NBIN * sizeof(unsigned), stream);
    hipLaunchKernelGGL(hist_kernel, dim3(pb), dim3(256), 0, stream, x, hist, n);
    hipLaunchKernelGGL(scan_kernel, dim3(1), dim3(1024), 0, stream, hist, base);
    hipLaunchKernelGGL(scatter_kernel, dim3(pb), dim3(256), 0, stream, x, base, pts, n);

    hipLaunchKernelGGL(gather_hash, dim3(pb * 8), dim3(256), 0, stream, pts, tables, ws2, n);
    hipLaunchKernelGGL(dense_finish, dim3(pb), dim3(256), 0, stream, pts, tables, ws2, out, n);
}

// Round 6
// 456.821 us; speedup vs baseline: 1.7608x; 1.0229x over previous
//
#include <hip/hip_runtime.h>

#define NLVL 16
#define T_MASK ((1u << 19) - 1)
#define NBIN 32768   // 32^3 Morton bins

typedef float v2f __attribute__((ext_vector_type(2)));
typedef float v4f __attribute__((ext_vector_type(4)));

// Runtime-indexed copies (hash kernel, fallback)
__constant__ int c_res[NLVL] = {16, 20, 25, 32, 40, 50, 64, 80,
                                101, 128, 161, 203, 256, 322, 406, 512};
__constant__ int c_off[NLVL] = {0, 4913, 14174, 31750, 67687, 136608, 269259, 543884,
                                1075325, 1599613, 2123901, 2648189, 3172477, 3696765, 4221053, 4745341};
__constant__ float c_grid[NLVL] = {
    (float)(2.0 / 16.0),  (float)(2.0 / 20.0),  (float)(2.0 / 25.0),  (float)(2.0 / 32.0),
    (float)(2.0 / 40.0),  (float)(2.0 / 50.0),  (float)(2.0 / 64.0),  (float)(2.0 / 80.0),
    (float)(2.0 / 101.0), (float)(2.0 / 128.0), (float)(2.0 / 161.0), (float)(2.0 / 203.0),
    (float)(2.0 / 256.0), (float)(2.0 / 322.0), (float)(2.0 / 406.0), (float)(2.0 / 512.0)};

// Compile-time copies (dense epilogue, fully unrolled -> immediates)
constexpr int kRes[8] = {16, 20, 25, 32, 40, 50, 64, 80};
constexpr int kOff[8] = {0, 4913, 14174, 31750, 67687, 136608, 269259, 543884};
constexpr float kGrid[8] = {
    (float)(2.0 / 16.0), (float)(2.0 / 20.0), (float)(2.0 / 25.0), (float)(2.0 / 32.0),
    (float)(2.0 / 40.0), (float)(2.0 / 50.0), (float)(2.0 / 64.0), (float)(2.0 / 80.0)};

__device__ __forceinline__ void dim_setup(float xv, float grid, int& b, float& w) {
    float xc = fminf(fmaxf(xv, -1.0f), 1.0f);
    float fb = floorf((xc + 1.0f) / grid);
    b = (int)fb;
    float vmin = fb * grid - 1.0f;
    w = (xv - vmin) / grid;   // original xv, exactly as reference
}

__device__ __forceinline__ unsigned part1by2(unsigned v) {
    v &= 0x3ff;
    v = (v | (v << 16)) & 0x030000FFu;
    v = (v | (v << 8))  & 0x0300F00Fu;
    v = (v | (v << 4))  & 0x030C30C3u;
    v = (v | (v << 2))  & 0x09249249u;
    return v;
}

__device__ __forceinline__ unsigned bin3(float a, float b, float c) {
    int ba = (int)floorf((a + 1.0f) * 16.0f); ba = ba < 0 ? 0 : (ba > 31 ? 31 : ba);
    int bb = (int)floorf((b + 1.0f) * 16.0f); bb = bb < 0 ? 0 : (bb > 31 ? 31 : bb);
    int bc = (int)floorf((c + 1.0f) * 16.0f); bc = bc < 0 ? 0 : (bc > 31 ? 31 : bc);
    return part1by2((unsigned)ba) | (part1by2((unsigned)bb) << 1) | (part1by2((unsigned)bc) << 2);
}

// ---- sort pipeline -------------------------------------------------------
__global__ __launch_bounds__(256) void hist_kernel(const float* __restrict__ x,
                                                   unsigned* __restrict__ hist, int n) {
    int p = (int)blockIdx.x * 256 + (int)threadIdx.x;
    if (p >= n) return;
    float a = x[3 * p], b = x[3 * p + 1], c = x[3 * p + 2];
    atomicAdd(&hist[bin3(a, b, c)], 1u);
}

__global__ __launch_bounds__(1024) void scan_kernel(const unsigned* __restrict__ hist,
                                                    unsigned* __restrict__ base) {
    __shared__ unsigned part[1024];
    const int t = (int)threadIdx.x;
    unsigned s = 0;
#pragma unroll
    for (int i = 0; i < NBIN / 1024; ++i) s += hist[t * (NBIN / 1024) + i];
    part[t] = s;
    __syncthreads();
    for (int off = 1; off < 1024; off <<= 1) {
        unsigned v = (t >= off) ? part[t - off] : 0u;
        __syncthreads();
        part[t] += v;
        __syncthreads();
    }
    unsigned run = part[t] - s;
    for (int i = 0; i < NBIN / 1024; ++i) {
        unsigned h = hist[t * (NBIN / 1024) + i];
        base[t * (NBIN / 1024) + i] = run;
        run += h;
    }
}

__global__ __launch_bounds__(256) void scatter_kernel(const float* __restrict__ x,
                                                      unsigned* __restrict__ base,
                                                      v4f* __restrict__ pts, int n) {
    int p = (int)blockIdx.x * 256 + (int)threadIdx.x;
    if (p >= n) return;
    float a = x[3 * p], b = x[3 * p + 1], c = x[3 * p + 2];
    unsigned slot = atomicAdd(&base[bin3(a, b, c)], 1u);
    v4f v; v.x = a; v.y = b; v.z = c; v.w = __int_as_float(p);
    pts[slot] = v;
}

// ---- hashed-level gather body (one point) --------------------------------
__device__ __forceinline__ v2f hash_one(const v4f pt, const v2f* __restrict__ tab,
                                        float grid) {
    int bx, by, bz;
    float wx, wy, wz;
    dim_setup(pt.x, grid, bx, wx);
    dim_setup(pt.y, grid, by, wy);
    dim_setup(pt.z, grid, bz, wz);

    const unsigned hx0 = (unsigned)bx, hx1 = (unsigned)(bx + 1);
    const unsigned hy0 = (unsigned)by * 2654435761u;
    const unsigned hy1 = (unsigned)(by + 1) * 2654435761u;
    const unsigned hz0 = (unsigned)bz * 805459861u;
    const unsigned hz1 = (unsigned)(bz + 1) * 805459861u;
    v2f e0 = tab[(hx0 ^ hy0 ^ hz0) & T_MASK];
    v2f e1 = tab[(hx0 ^ hy0 ^ hz1) & T_MASK];
    v2f e2 = tab[(hx0 ^ hy1 ^ hz0) & T_MASK];
    v2f e3 = tab[(hx0 ^ hy1 ^ hz1) & T_MASK];
    v2f e4 = tab[(hx1 ^ hy0 ^ hz0) & T_MASK];
    v2f e5 = tab[(hx1 ^ hy0 ^ hz1) & T_MASK];
    v2f e6 = tab[(hx1 ^ hy1 ^ hz0) & T_MASK];
    v2f e7 = tab[(hx1 ^ hy1 ^ hz1) & T_MASK];

    const float ox = 1.0f - wx, oy = 1.0f - wy, oz = 1.0f - wz;
    v2f c00 = e0 * ox + e4 * wx;
    v2f c01 = e1 * ox + e5 * wx;
    v2f c10 = e2 * ox + e6 * wx;
    v2f c11 = e3 * ox + e7 * wx;
    v2f c0 = c00 * oy + c10 * wy;
    v2f c1 = c01 * oy + c11 * wy;
    return c0 * oz + c1 * wz;
}

// ---- hashed levels: one block = one level x 512 sorted points (2/thread).
// level = (blockIdx&7)+8 -> XCD k serves exactly one 4 MB table (L2-resident).
// 2 points/thread doubles in-flight gathers -> pushes L2 request rate toward
// the ~16 req/cy/XCD port ceiling (r5 measured 13.1).
__global__ __launch_bounds__(256) void gather_hash(const v4f* __restrict__ pts,
                                                   const float* __restrict__ tables,
                                                   v2f* __restrict__ ws2, int n) {
    const int level = (int)(blockIdx.x & 7) + 8;
    const int pA = (int)(blockIdx.x >> 3) * 512 + (int)threadIdx.x;
    const int pB = pA + 256;
    const float grid = c_grid[level];
    const v2f* __restrict__ tab = reinterpret_cast<const v2f*>(tables) + c_off[level];
    v2f* __restrict__ dst = ws2 + (size_t)(level - 8) * n;

    if (pB < n) {
        const v4f ptA = __builtin_nontemporal_load(&pts[pA]);
        const v4f ptB = __builtin_nontemporal_load(&pts[pB]);
        v2f rA = hash_one(ptA, tab, grid);
        v2f rB = hash_one(ptB, tab, grid);
        __builtin_nontemporal_store(rA, &dst[pA]);
        __builtin_nontemporal_store(rB, &dst[pB]);
    } else if (pA < n) {
        const v4f ptA = __builtin_nontemporal_load(&pts[pA]);
        v2f rA = hash_one(ptA, tab, grid);
        __builtin_nontemporal_store(rA, &dst[pA]);
    }
}

// ---- dense levels + final row assembly: one thread = one sorted point.
// ws2 NT loads issued FIRST (longest latency), dense table loads (L2-hit)
// drain underneath. launch_bounds(256,4) -> <=128 VGPR so the compiler can
// pipeline several levels' corner loads (r4's 48 VGPR over-throttled it).
__global__ __launch_bounds__(256, 4) void dense_finish(const v4f* __restrict__ pts,
                                                       const float* __restrict__ tables,
                                                       const v2f* __restrict__ ws2,
                                                       float* __restrict__ out, int n) {
    const int nb = (int)gridDim.x;
    const int bid = (int)blockIdx.x;
    const int q = nb >> 3, r = nb & 7;
    const int xcd = bid & 7, j = bid >> 3;
    const int nbid = (xcd < r) ? xcd * (q + 1) + j : r * (q + 1) + (xcd - r) * q + j;
    const int p = nbid * 256 + (int)threadIdx.x;
    if (p >= n) return;

    // issue the long-latency streaming loads first
    v2f h[8];
#pragma unroll
    for (int l = 0; l < 8; ++l)
        h[l] = __builtin_nontemporal_load(&ws2[(size_t)l * n + p]);

    const v4f pt = __builtin_nontemporal_load(&pts[p]);
    const int org = __float_as_int(pt.w);

    v2f d[8];
#pragma unroll
    for (int l = 0; l < 8; ++l) {
        const int res = kRes[l];
        const float grid = kGrid[l];
        const v2f* __restrict__ tab = reinterpret_cast<const v2f*>(tables) + kOff[l];
        int bx, by, bz;
        float wx, wy, wz;
        dim_setup(pt.x, grid, bx, wx);
        dim_setup(pt.y, grid, by, wy);
        dim_setup(pt.z, grid, bz, wz);
        const int r2 = res * res;
        const int base = bx * r2 + by * res + bz;
        v2f e0 = tab[base];            v2f e1 = tab[base + 1];
        v2f e2 = tab[base + res];      v2f e3 = tab[base + res + 1];
        v2f e4 = tab[base + r2];       v2f e5 = tab[base + r2 + 1];
        v2f e6 = tab[base + r2 + res]; v2f e7 = tab[base + r2 + res + 1];
        const float ox = 1.0f - wx, oy = 1.0f - wy, oz = 1.0f - wz;
        v2f c00 = e0 * ox + e4 * wx;
        v2f c01 = e1 * ox + e5 * wx;
        v2f c10 = e2 * ox + e6 * wx;
        v2f c11 = e3 * ox + e7 * wx;
        v2f c0 = c00 * oy + c10 * wy;
        v2f c1 = c01 * oy + c11 * wy;
        d[l] = c0 * oz + c1 * wz;
    }

    v4f* dst = reinterpret_cast<v4f*>(out + (size_t)org * 32);
#pragma unroll
    for (int k = 0; k < 4; ++k) {
        v4f v; v.x = d[2 * k].x; v.y = d[2 * k].y; v.z = d[2 * k + 1].x; v.w = d[2 * k + 1].y;
        dst[k] = v;                       // cached store -> L2 write-combining
    }
#pragma unroll
    for (int k = 0; k < 4; ++k) {
        v4f v; v.x = h[2 * k].x; v.y = h[2 * k].y; v.z = h[2 * k + 1].x; v.w = h[2 * k + 1].y;
        dst[4 + k] = v;
    }
}

// ---- safety fallback (ws too small) --------------------------------------
__global__ __launch_bounds__(256) void hashgrid_direct(const float* __restrict__ x,
                                                       const float* __restrict__ tables,
                                                       float* __restrict__ out, int n_points) {
    const int t = (int)blockIdx.x * 256 + (int)threadIdx.x;
    const int p = t >> 4;
    if (p >= n_points) return;
    const int l = t & 15;
    const float xx = x[p * 3 + 0], xy = x[p * 3 + 1], xz = x[p * 3 + 2];
    const int res = c_res[l];
    const float grid = c_grid[l];
    const v2f* __restrict__ tab = reinterpret_cast<const v2f*>(tables) + c_off[l];
    int bx, by, bz; float wx, wy, wz;
    dim_setup(xx, grid, bx, wx);
    dim_setup(xy, grid, by, wy);
    dim_setup(xz, grid, bz, wz);
    v2f e0, e1, e2, e3, e4, e5, e6, e7;
    if (l < 8) {
        const int r2 = res * res;
        const int base = bx * r2 + by * res + bz;
        e0 = tab[base];            e1 = tab[base + 1];
        e2 = tab[base + res];      e3 = tab[base + res + 1];
        e4 = tab[base + r2];       e5 = tab[base + r2 + 1];
        e6 = tab[base + r2 + res]; e7 = tab[base + r2 + res + 1];
    } else {
        const unsigned hx0 = (unsigned)bx, hx1 = (unsigned)(bx + 1);
        const unsigned hy0 = (unsigned)by * 2654435761u, hy1 = (unsigned)(by + 1) * 2654435761u;
        const unsigned hz0 = (unsigned)bz * 805459861u,  hz1 = (unsigned)(bz + 1) * 805459861u;
        e0 = tab[(hx0 ^ hy0 ^ hz0) & T_MASK]; e1 = tab[(hx0 ^ hy0 ^ hz1) & T_MASK];
        e2 = tab[(hx0 ^ hy1 ^ hz0) & T_MASK]; e3 = tab[(hx0 ^ hy1 ^ hz1) & T_MASK];
        e4 = tab[(hx1 ^ hy0 ^ hz0) & T_MASK]; e5 = tab[(hx1 ^ hy0 ^ hz1) & T_MASK];
        e6 = tab[(hx1 ^ hy1 ^ hz0) & T_MASK]; e7 = tab[(hx1 ^ hy1 ^ hz1) & T_MASK];
    }
    const float ox = 1.0f - wx, oy = 1.0f - wy, oz = 1.0f - wz;
    v2f c00 = e0 * ox + e4 * wx, c01 = e1 * ox + e5 * wx;
    v2f c10 = e2 * ox + e6 * wx, c11 = e3 * ox + e7 * wx;
    v2f c0 = c00 * oy + c10 * wy, c1 = c01 * oy + c11 * wy;
    v2f r = c0 * oz + c1 * wz;
    reinterpret_cast<v2f*>(out)[(size_t)p * NLVL + l] = r;
}

extern "C" void kernel_launch(void* const* d_in, const int* in_sizes, int n_in,
                              void* d_out, int out_size, void* d_ws, size_t ws_size,
                              hipStream_t stream) {
    const float* x = (const float*)d_in[0];
    const float* tables = (const float*)d_in[1];
    float* out = (float*)d_out;
    const int n = in_sizes[0] / 3;

    // ws layout: hist(128K) | base(128K) | pts float4 (16n) | ws2 (8 levels * 8B * n)
    const size_t need = 262144 + (size_t)n * 16 + (size_t)n * 64;
    if (ws_size < need) {
        const int blocks = (n * NLVL + 255) / 256;
        hipLaunchKernelGGL(hashgrid_direct, dim3(blocks), dim3(256), 0, stream, x, tables, out, n);
        return;
    }

    char* w = (char*)d_ws;
    unsigned* hist = (unsigned*)w;
    unsigned* base = (unsigned*)(w + 131072);
    v4f* pts = (v4f*)(w + 262144);
    v2f* ws2 = (v2f*)(w + 262144 + (size_t)n * 16);

    const int pb = (n + 255) / 256;          // 256-pt blocks
    const int hb = (n + 511) / 512;          // 512-pt blocks (gather_hash)

    hipMemsetAsync(hist, 0, NBIN * sizeof(unsigned), stream);
    hipLaunchKernelGGL(hist_kernel, dim3(pb), dim3(256), 0, stream, x, hist, n);
    hipLaunchKernelGGL(scan_kernel, dim3(1), dim3(1024), 0, stream, hist, base);
    hipLaunchKernelGGL(scatter_kernel, dim3(pb), dim3(256), 0, stream, x, base, pts, n);

    hipLaunchKernelGGL(gather_hash, dim3(hb * 8), dim3(256), 0, stream, pts, tables, ws2, n);
    hipLaunchKernelGGL(dense_finish, dim3(pb), dim3(256), 0, stream, pts, tables, ws2, out, n);
}

// Round 7
// 430.351 us; speedup vs baseline: 1.8692x; 1.0615x over previous
//
#include <hip/hip_runtime.h>

#define NLVL 16
#define T_MASK ((1u << 19) - 1)
#define NBIN 32768   // 32^3 Morton bins

typedef float v2f __attribute__((ext_vector_type(2)));
typedef float v4f __attribute__((ext_vector_type(4)));

// Runtime-indexed copies (hash kernel, fallback)
__constant__ int c_res[NLVL] = {16, 20, 25, 32, 40, 50, 64, 80,
                                101, 128, 161, 203, 256, 322, 406, 512};
__constant__ int c_off[NLVL] = {0, 4913, 14174, 31750, 67687, 136608, 269259, 543884,
                                1075325, 1599613, 2123901, 2648189, 3172477, 3696765, 4221053, 4745341};
__constant__ float c_grid[NLVL] = {
    (float)(2.0 / 16.0),  (float)(2.0 / 20.0),  (float)(2.0 / 25.0),  (float)(2.0 / 32.0),
    (float)(2.0 / 40.0),  (float)(2.0 / 50.0),  (float)(2.0 / 64.0),  (float)(2.0 / 80.0),
    (float)(2.0 / 101.0), (float)(2.0 / 128.0), (float)(2.0 / 161.0), (float)(2.0 / 203.0),
    (float)(2.0 / 256.0), (float)(2.0 / 322.0), (float)(2.0 / 406.0), (float)(2.0 / 512.0)};

// Compile-time copies (dense epilogue, fully unrolled -> immediates)
constexpr int kRes[8] = {16, 20, 25, 32, 40, 50, 64, 80};
constexpr int kOff[8] = {0, 4913, 14174, 31750, 67687, 136608, 269259, 543884};
constexpr float kGrid[8] = {
    (float)(2.0 / 16.0), (float)(2.0 / 20.0), (float)(2.0 / 25.0), (float)(2.0 / 32.0),
    (float)(2.0 / 40.0), (float)(2.0 / 50.0), (float)(2.0 / 64.0), (float)(2.0 / 80.0)};

__device__ __forceinline__ void dim_setup(float xv, float grid, int& b, float& w) {
    float xc = fminf(fmaxf(xv, -1.0f), 1.0f);
    float fb = floorf((xc + 1.0f) / grid);
    b = (int)fb;
    float vmin = fb * grid - 1.0f;
    w = (xv - vmin) / grid;   // original xv, exactly as reference
}

__device__ __forceinline__ unsigned part1by2(unsigned v) {
    v &= 0x3ff;
    v = (v | (v << 16)) & 0x030000FFu;
    v = (v | (v << 8))  & 0x0300F00Fu;
    v = (v | (v << 4))  & 0x030C30C3u;
    v = (v | (v << 2))  & 0x09249249u;
    return v;
}

__device__ __forceinline__ unsigned bin3(float a, float b, float c) {
    int ba = (int)floorf((a + 1.0f) * 16.0f); ba = ba < 0 ? 0 : (ba > 31 ? 31 : ba);
    int bb = (int)floorf((b + 1.0f) * 16.0f); bb = bb < 0 ? 0 : (bb > 31 ? 31 : bb);
    int bc = (int)floorf((c + 1.0f) * 16.0f); bc = bc < 0 ? 0 : (bc > 31 ? 31 : bc);
    return part1by2((unsigned)ba) | (part1by2((unsigned)bb) << 1) | (part1by2((unsigned)bc) << 2);
}

// ---- sort pipeline -------------------------------------------------------
__global__ __launch_bounds__(256) void hist_kernel(const float* __restrict__ x,
                                                   unsigned* __restrict__ hist, int n) {
    int p = (int)blockIdx.x * 256 + (int)threadIdx.x;
    if (p >= n) return;
    float a = x[3 * p], b = x[3 * p + 1], c = x[3 * p + 2];
    atomicAdd(&hist[bin3(a, b, c)], 1u);
}

__global__ __launch_bounds__(1024) void scan_kernel(const unsigned* __restrict__ hist,
                                                    unsigned* __restrict__ base) {
    __shared__ unsigned part[1024];
    const int t = (int)threadIdx.x;
    unsigned s = 0;
#pragma unroll
    for (int i = 0; i < NBIN / 1024; ++i) s += hist[t * (NBIN / 1024) + i];
    part[t] = s;
    __syncthreads();
    for (int off = 1; off < 1024; off <<= 1) {
        unsigned v = (t >= off) ? part[t - off] : 0u;
        __syncthreads();
        part[t] += v;
        __syncthreads();
    }
    unsigned run = part[t] - s;
    for (int i = 0; i < NBIN / 1024; ++i) {
        unsigned h = hist[t * (NBIN / 1024) + i];
        base[t * (NBIN / 1024) + i] = run;
        run += h;
    }
}

__global__ __launch_bounds__(256) void scatter_kernel(const float* __restrict__ x,
                                                      unsigned* __restrict__ base,
                                                      v4f* __restrict__ pts, int n) {
    int p = (int)blockIdx.x * 256 + (int)threadIdx.x;
    if (p >= n) return;
    float a = x[3 * p], b = x[3 * p + 1], c = x[3 * p + 2];
    unsigned slot = atomicAdd(&base[bin3(a, b, c)], 1u);
    v4f v; v.x = a; v.y = b; v.z = c; v.w = __int_as_float(p);
    pts[slot] = v;
}

// ---- hashed levels: one block = one level x 256 sorted points (1/thread;
// r6 showed 2/thread deepens L2 queues and is slightly worse).
// level = (blockIdx&7)+8 -> XCD k serves exactly one 4 MB table (L2-resident).
__global__ __launch_bounds__(256) void gather_hash(const v4f* __restrict__ pts,
                                                   const float* __restrict__ tables,
                                                   v2f* __restrict__ ws2, int n) {
    const int level = (int)(blockIdx.x & 7) + 8;
    const int p = (int)(blockIdx.x >> 3) * 256 + (int)threadIdx.x;
    if (p >= n) return;

    const v4f pt = __builtin_nontemporal_load(&pts[p]);   // single-use stream
    const float grid = c_grid[level];
    const v2f* __restrict__ tab = reinterpret_cast<const v2f*>(tables) + c_off[level];

    int bx, by, bz;
    float wx, wy, wz;
    dim_setup(pt.x, grid, bx, wx);
    dim_setup(pt.y, grid, by, wy);
    dim_setup(pt.z, grid, bz, wz);

    const unsigned hx0 = (unsigned)bx, hx1 = (unsigned)(bx + 1);
    const unsigned hy0 = (unsigned)by * 2654435761u;
    const unsigned hy1 = (unsigned)(by + 1) * 2654435761u;
    const unsigned hz0 = (unsigned)bz * 805459861u;
    const unsigned hz1 = (unsigned)(bz + 1) * 805459861u;
    v2f e0 = tab[(hx0 ^ hy0 ^ hz0) & T_MASK];
    v2f e1 = tab[(hx0 ^ hy0 ^ hz1) & T_MASK];
    v2f e2 = tab[(hx0 ^ hy1 ^ hz0) & T_MASK];
    v2f e3 = tab[(hx0 ^ hy1 ^ hz1) & T_MASK];
    v2f e4 = tab[(hx1 ^ hy0 ^ hz0) & T_MASK];
    v2f e5 = tab[(hx1 ^ hy0 ^ hz1) & T_MASK];
    v2f e6 = tab[(hx1 ^ hy1 ^ hz0) & T_MASK];
    v2f e7 = tab[(hx1 ^ hy1 ^ hz1) & T_MASK];

    const float ox = 1.0f - wx, oy = 1.0f - wy, oz = 1.0f - wz;
    v2f c00 = e0 * ox + e4 * wx;
    v2f c01 = e1 * ox + e5 * wx;
    v2f c10 = e2 * ox + e6 * wx;
    v2f c11 = e3 * ox + e7 * wx;
    v2f c0 = c00 * oy + c10 * wy;
    v2f c1 = c01 * oy + c11 * wy;
    v2f r = c0 * oz + c1 * wz;

    // lane-contiguous -> wave-coalesced full lines; NT keeps tables resident
    __builtin_nontemporal_store(r, &ws2[(size_t)(level - 8) * n + p]);
}

// ---- dense levels + final row assembly -----------------------------------
// One thread = one sorted point, computes levels 0-7, merges hashed results.
// Output rows are staged in LDS then written with 8 lanes per row so every
// 64 B line is covered by ONE store instruction: 2M store requests vs 8M for
// the per-thread scattered 16 B pattern (r6 analysis: stores were ~40% of
// this kernel's L2-request budget).
#define ROWSTRIDE 36   // floats per LDS row slot (144 B, keeps 16B alignment)
__global__ __launch_bounds__(256, 4) void dense_finish(const v4f* __restrict__ pts,
                                                       const float* __restrict__ tables,
                                                       const v2f* __restrict__ ws2,
                                                       float* __restrict__ out, int n) {
    __shared__ float lrow[256 * ROWSTRIDE];   // 36.9 KB
    __shared__ int lorg[256];

    const int nb = (int)gridDim.x;
    const int bid = (int)blockIdx.x;
    const int q = nb >> 3, r = nb & 7;
    const int xcd = bid & 7, j = bid >> 3;
    const int nbid = (xcd < r) ? xcd * (q + 1) + j : r * (q + 1) + (xcd - r) * q + j;
    const int tid = (int)threadIdx.x;
    const int base_p = nbid * 256;
    const int p = base_p + tid;

    if (p < n) {
        // issue the long-latency streaming loads first
        v2f h[8];
#pragma unroll
        for (int l = 0; l < 8; ++l)
            h[l] = __builtin_nontemporal_load(&ws2[(size_t)l * n + p]);

        const v4f pt = __builtin_nontemporal_load(&pts[p]);
        lorg[tid] = __float_as_int(pt.w);

        v2f d[8];
#pragma unroll
        for (int l = 0; l < 8; ++l) {
            const int res = kRes[l];
            const float grid = kGrid[l];
            const v2f* __restrict__ tab = reinterpret_cast<const v2f*>(tables) + kOff[l];
            int bx, by, bz;
            float wx, wy, wz;
            dim_setup(pt.x, grid, bx, wx);
            dim_setup(pt.y, grid, by, wy);
            dim_setup(pt.z, grid, bz, wz);
            const int r2 = res * res;
            const int base = bx * r2 + by * res + bz;
            v2f e0 = tab[base];            v2f e1 = tab[base + 1];
            v2f e2 = tab[base + res];      v2f e3 = tab[base + res + 1];
            v2f e4 = tab[base + r2];       v2f e5 = tab[base + r2 + 1];
            v2f e6 = tab[base + r2 + res]; v2f e7 = tab[base + r2 + res + 1];
            const float ox = 1.0f - wx, oy = 1.0f - wy, oz = 1.0f - wz;
            v2f c00 = e0 * ox + e4 * wx;
            v2f c01 = e1 * ox + e5 * wx;
            v2f c10 = e2 * ox + e6 * wx;
            v2f c11 = e3 * ox + e7 * wx;
            v2f c0 = c00 * oy + c10 * wy;
            v2f c1 = c01 * oy + c11 * wy;
            d[l] = c0 * oz + c1 * wz;
        }

        float* myrow = &lrow[tid * ROWSTRIDE];
#pragma unroll
        for (int k = 0; k < 4; ++k) {
            v4f v; v.x = d[2 * k].x; v.y = d[2 * k].y; v.z = d[2 * k + 1].x; v.w = d[2 * k + 1].y;
            *reinterpret_cast<v4f*>(myrow + 4 * k) = v;
        }
#pragma unroll
        for (int k = 0; k < 4; ++k) {
            v4f v; v.x = h[2 * k].x; v.y = h[2 * k].y; v.z = h[2 * k + 1].x; v.w = h[2 * k + 1].y;
            *reinterpret_cast<v4f*>(myrow + 16 + 4 * k) = v;
        }
    }
    __syncthreads();

    // store phase: 8 consecutive lanes write one row's 128 B contiguously
    const int c = tid & 7;          // 16B chunk within row
    const int r0 = tid >> 3;        // 0..31
#pragma unroll
    for (int s = 0; s < 8; ++s) {
        const int rr = s * 32 + r0;                 // row within block
        if (base_p + rr < n) {
            v4f v = *reinterpret_cast<const v4f*>(&lrow[rr * ROWSTRIDE + c * 4]);
            const int o = lorg[rr];
            *reinterpret_cast<v4f*>(out + (size_t)o * 32 + c * 4) = v;
        }
    }
}

// ---- safety fallback (ws too small) --------------------------------------
__global__ __launch_bounds__(256) void hashgrid_direct(const float* __restrict__ x,
                                                       const float* __restrict__ tables,
                                                       float* __restrict__ out, int n_points) {
    const int t = (int)blockIdx.x * 256 + (int)threadIdx.x;
    const int p = t >> 4;
    if (p >= n_points) return;
    const int l = t & 15;
    const float xx = x[p * 3 + 0], xy = x[p * 3 + 1], xz = x[p * 3 + 2];
    const int res = c_res[l];
    const float grid = c_grid[l];
    const v2f* __restrict__ tab = reinterpret_cast<const v2f*>(tables) + c_off[l];
    int bx, by, bz; float wx, wy, wz;
    dim_setup(xx, grid, bx, wx);
    dim_setup(xy, grid, by, wy);
    dim_setup(xz, grid, bz, wz);
    v2f e0, e1, e2, e3, e4, e5, e6, e7;
    if (l < 8) {
        const int r2 = res * res;
        const int base = bx * r2 + by * res + bz;
        e0 = tab[base];            e1 = tab[base + 1];
        e2 = tab[base + res];      e3 = tab[base + res + 1];
        e4 = tab[base + r2];       e5 = tab[base + r2 + 1];
        e6 = tab[base + r2 + res]; e7 = tab[base + r2 + res + 1];
    } else {
        const unsigned hx0 = (unsigned)bx, hx1 = (unsigned)(bx + 1);
        const unsigned hy0 = (unsigned)by * 2654435761u, hy1 = (unsigned)(by + 1) * 2654435761u;
        const unsigned hz0 = (unsigned)bz * 805459861u,  hz1 = (unsigned)(bz + 1) * 805459861u;
        e0 = tab[(hx0 ^ hy0 ^ hz0) & T_MASK]; e1 = tab[(hx0 ^ hy0 ^ hz1) & T_MASK];
        e2 = tab[(hx0 ^ hy1 ^ hz0) & T_MASK]; e3 = tab[(hx0 ^ hy1 ^ hz1) & T_MASK];
        e4 = tab[(hx1 ^ hy0 ^ hz0) & T_MASK]; e5 = tab[(hx1 ^ hy0 ^ hz1) & T_MASK];
        e6 = tab[(hx1 ^ hy1 ^ hz0) & T_MASK]; e7 = tab[(hx1 ^ hy1 ^ hz1) & T_MASK];
    }
    const float ox = 1.0f - wx, oy = 1.0f - wy, oz = 1.0f - wz;
    v2f c00 = e0 * ox + e4 * wx, c01 = e1 * ox + e5 * wx;
    v2f c10 = e2 * ox + e6 * wx, c11 = e3 * ox + e7 * wx;
    v2f c0 = c00 * oy + c10 * wy, c1 = c01 * oy + c11 * wy;
    v2f r = c0 * oz + c1 * wz;
    reinterpret_cast<v2f*>(out)[(size_t)p * NLVL + l] = r;
}

extern "C" void kernel_launch(void* const* d_in, const int* in_sizes, int n_in,
                              void* d_out, int out_size, void* d_ws, size_t ws_size,
                              hipStream_t stream) {
    const float* x = (const float*)d_in[0];
    const float* tables = (const float*)d_in[1];
    float* out = (float*)d_out;
    const int n = in_sizes[0] / 3;

    // ws layout: hist(128K) | base(128K) | pts float4 (16n) | ws2 (8 levels * 8B * n)
    const size_t need = 262144 + (size_t)n * 16 + (size_t)n * 64;
    if (ws_size < need) {
        const int blocks = (n * NLVL + 255) / 256;
        hipLaunchKernelGGL(hashgrid_direct, dim3(blocks), dim3(256), 0, stream, x, tables, out, n);
        return;
    }

    char* w = (char*)d_ws;
    unsigned* hist = (unsigned*)w;
    unsigned* base = (unsigned*)(w + 131072);
    v4f* pts = (v4f*)(w + 262144);
    v2f* ws2 = (v2f*)(w + 262144 + (size_t)n * 16);

    const int pb = (n + 255) / 256;

    hipMemsetAsync(hist, 0, NBIN * sizeof(unsigned), stream);
    hipLaunchKernelGGL(hist_kernel, dim3(pb), dim3(256), 0, stream, x, hist, n);
    hipLaunchKernelGGL(scan_kernel, dim3(1), dim3(1024), 0, stream, hist, base);
    hipLaunchKernelGGL(scatter_kernel, dim3(pb), dim3(256), 0, stream, x, base, pts, n);

    hipLaunchKernelGGL(gather_hash, dim3(pb * 8), dim3(256), 0, stream, pts, tables, ws2, n);
    hipLaunchKernelGGL(dense_finish, dim3(pb), dim3(256), 0, stream, pts, tables, ws2, out, n);
}